// Round 4
// baseline (128.062 us; speedup 1.0000x reference)
//
#include <hip/hip_runtime.h>

// VQ color lookup, round 3.
// R2 post-mortem: compiler scalarized the f2 math (extracts for the compare
// chain defeat vector codegen) -> ~30 VALU/(px,k), issue-bound at 73% with
// only 16 waves/CU. Fix:
//  - pack along the PALETTE axis: palette prepped as pairs (k,k+1) in f2
//    SoA form; per-pixel broadcasts built once outside the loop; palette
//    pair operands are wave-uniform -> SGPR pairs (one scalar operand per
//    VOP3P is legal).
//  - force v_pk_mul_f32 / v_pk_add_f32 via inline asm: 8 packed ops per
//    k-pair + 6 scalar cmp/cndmask = 7 VALU per (px,k).
//  - 1 pixel/thread -> 8192 waves -> 32 waves/CU (2x latency hiding).
// Numerics identical to numpy ref: same left-assoc order, IEEE per-lane
// packed ops, cross+cross == 2*cross exactly. R1/R2 passed absmax 0.0.

#define KPAL 512
#define HW   65536            // 256*256
#define CHW  (3 * HW)
#define NPIX (8 * HW)         // 524288 pixels
#define NELEM (NPIX * 3)      // 1572864 output color elements

typedef float f2 __attribute__((ext_vector_type(2)));

struct __align__(32) Pair {   // palette entries 2j (lo) and 2j+1 (hi)
    f2 x, y, z, w;            // w = ||t||^2 (contract-off)
};

static __device__ __forceinline__ f2 pk_mul_s(f2 a, f2 b) {
    f2 d; asm("v_pk_mul_f32 %0, %1, %2" : "=v"(d) : "v"(a), "s"(b)); return d;
}
static __device__ __forceinline__ f2 pk_add_s(f2 a, f2 b) {
    f2 d; asm("v_pk_add_f32 %0, %1, %2" : "=v"(d) : "v"(a), "s"(b)); return d;
}
static __device__ __forceinline__ f2 pk_add_v(f2 a, f2 b) {
    f2 d; asm("v_pk_add_f32 %0, %1, %2" : "=v"(d) : "v"(a), "v"(b)); return d;
}
static __device__ __forceinline__ f2 pk_sub_v(f2 a, f2 b) {  // a - b
    f2 d; asm("v_pk_add_f32 %0, %1, %2 neg_lo:[0,1] neg_hi:[0,1]"
              : "=v"(d) : "v"(a), "v"(b)); return d;
}

// Pack table[512*3] into 256 Pairs in d_ws.
__global__ __launch_bounds__(256)
void prep_kernel(const float* __restrict__ table, Pair* __restrict__ pal)
{
    const int j = threadIdx.x;        // one block of 256
    const float a0 = table[6 * j + 0], a1 = table[6 * j + 1], a2 = table[6 * j + 2];
    const float b0 = table[6 * j + 3], b1 = table[6 * j + 4], b2 = table[6 * j + 5];
    float aw, bw;
    {
#pragma clang fp contract(off)
        aw = a0 * a0 + a1 * a1 + a2 * a2;
        bw = b0 * b0 + b1 * b1 + b2 * b2;
    }
    Pair p;
    p.x = (f2){a0, b0};
    p.y = (f2){a1, b1};
    p.z = (f2){a2, b2};
    p.w = (f2){aw, bw};
    pal[j] = p;
}

__global__ __launch_bounds__(256)
void vq_kernel(const float* __restrict__ z,
               const Pair* __restrict__ pal,
               const float* __restrict__ table,
               float* __restrict__ out,
               float* __restrict__ loss)
{
    const int t    = threadIdx.x;
    const int idx  = blockIdx.x * 256 + t;   // pixel id
    const int b    = idx >> 16;
    const int p    = idx & (HW - 1);
    const int base = b * CHW + p;

    const float z0 = z[base];
    const float z1 = z[base + HW];
    const float z2 = z[base + 2 * HW];
    float z2s;
    {
#pragma clang fp contract(off)
        z2s = z0 * z0 + z1 * z1 + z2 * z2;
    }
    const f2 Z0 = (f2){z0, z0};
    const f2 Z1 = (f2){z1, z1};
    const f2 Z2 = (f2){z2, z2};
    const f2 ZS = (f2){z2s, z2s};

    float best = 3.4e38f;
    int   bi   = 0;
#pragma unroll 4
    for (int j = 0; j < KPAL / 2; ++j) {
        const Pair c = pal[j];               // uniform -> s_load, SGPR pairs
        f2 m0 = pk_mul_s(Z0, c.x);           // z0*cx            (k, k+1)
        f2 a0 = pk_add_v(m0, pk_mul_s(Z1, c.y));   // + z1*cy   left-assoc
        f2 a1 = pk_add_v(a0, pk_mul_s(Z2, c.z));   // + z2*cz = cross
        f2 n  = pk_add_v(a1, a1);            // 2*cross (exact)
        f2 s0 = pk_sub_v(ZS, n);             // z2s - 2*cross
        f2 d  = pk_add_s(s0, c.w);           // + t2
        if (d.x < best) { best = d.x; bi = 2 * j; }      // strict <: first-
        if (d.y < best) { best = d.y; bi = 2 * j + 1; }  // index tie-break
    }

    const float c0 = table[3 * bi + 0];      // divergent gather, L1-hot 6 KB
    const float c1 = table[3 * bi + 1];
    const float c2 = table[3 * bi + 2];
    out[base]          = c0;
    out[base + HW]     = c1;
    out[base + 2 * HW] = c2;

    const float d0 = c0 - z0, d1 = c1 - z1, d2v = c2 - z2;
    float lsum = d0 * d0 + d1 * d1 + d2v * d2v;

    for (int off = 32; off > 0; off >>= 1)
        lsum += __shfl_down(lsum, off);

    __shared__ float wsum[4];
    const int wid = t >> 6;
    if ((t & 63) == 0) wsum[wid] = lsum;
    __syncthreads();
    if (t == 0) {
        const float s = wsum[0] + wsum[1] + wsum[2] + wsum[3];
        atomicAdd(loss, s * (11.0f / (float)NELEM));
    }
}

extern "C" void kernel_launch(void* const* d_in, const int* in_sizes, int n_in,
                              void* d_out, int out_size, void* d_ws, size_t ws_size,
                              hipStream_t stream)
{
    const float* z     = (const float*)d_in[0];
    const float* table = (const float*)d_in[1];
    float* out  = (float*)d_out;
    float* loss = out + NELEM;
    Pair*  pal  = (Pair*)d_ws;               // 256 * 32 B = 8 KB scratch

    hipMemsetAsync(loss, 0, sizeof(float), stream);
    prep_kernel<<<1, 256, 0, stream>>>(table, pal);
    vq_kernel<<<NPIX / 256, 256, 0, stream>>>(z, pal, table, out, loss);
}

// Round 5
// 121.474 us; speedup vs baseline: 1.0542x; 1.0542x over previous
//
#include <hip/hip_runtime.h>

// VQ color lookup, round 4.
// R2 and R3 hit an identical 73 µs wall with different inner loops ->
// shared bottleneck: palette delivered over the per-lane VMEM/L1 path
// (~64 B/cyc/CU return BW ≈ 55 µs floor), not the packed math.
// Fix: palette lives in LDS, read at a wave-uniform address ->
// ds_read_b128 broadcast (free, no conflict, ~12 cyc — m134/m136), and
// each fetch is reused for P=4 pixels/thread:
//   DS  : 8 waves/CU x 512 b128 x 12 cyc ~ 20 µs
//   VALU: 2 waves/SIMD x 256 pairs x 56 pk/sel x 2 cyc ~ 24 µs
// Packed fp32 via inline asm (all-VGPR operands; producers locked so the
// .x/.y extracts can't scalarize the chain). Distance formula bit-identical
// to numpy (contract off, left-assoc, 2*cross == cr+cr exact): R1-R3 all
// passed with absmax 0.0.

#define KPAL 512
#define HW   65536            // 256*256
#define CHW  (3 * HW)
#define NPIX (8 * HW)         // 524288 pixels
#define NELEM (NPIX * 3)      // 1572864 output color elements
#define PPT  4                // pixels per thread

typedef float f2 __attribute__((ext_vector_type(2)));

struct __align__(32) Pair {   // palette entries 2j (lo half) and 2j+1 (hi)
    f2 x, y, z, w;            // w = ||t||^2 (contract-off)
};

static __device__ __forceinline__ f2 pk_mul(f2 a, f2 b) {
    f2 d; asm("v_pk_mul_f32 %0, %1, %2" : "=v"(d) : "v"(a), "v"(b)); return d;
}
static __device__ __forceinline__ f2 pk_add(f2 a, f2 b) {
    f2 d; asm("v_pk_add_f32 %0, %1, %2" : "=v"(d) : "v"(a), "v"(b)); return d;
}
static __device__ __forceinline__ f2 pk_sub(f2 a, f2 b) {  // a - b
    f2 d; asm("v_pk_add_f32 %0, %1, %2 neg_lo:[0,1] neg_hi:[0,1]"
              : "=v"(d) : "v"(a), "v"(b)); return d;
}

__global__ __launch_bounds__(256)
void vq_kernel(const float* __restrict__ z,
               const float* __restrict__ table,
               float* __restrict__ out,
               float* __restrict__ loss)
{
    __shared__ Pair stab[KPAL / 2];   // 256 pairs, 8 KB
    const int t = threadIdx.x;

    // Stage palette pairs into LDS (one pair per thread, one-time cost).
    {
        const int j = t;
        const float a0 = table[6 * j + 0], a1 = table[6 * j + 1], a2 = table[6 * j + 2];
        const float b0 = table[6 * j + 3], b1 = table[6 * j + 4], b2 = table[6 * j + 5];
        float aw, bw;
        {
#pragma clang fp contract(off)
            aw = a0 * a0 + a1 * a1 + a2 * a2;
            bw = b0 * b0 + b1 * b1 + b2 * b2;
        }
        Pair p;
        p.x = (f2){a0, b0};
        p.y = (f2){a1, b1};
        p.z = (f2){a2, b2};
        p.w = (f2){aw, bw};
        stab[j] = p;
    }
    __syncthreads();

    // P=4 pixels per thread: idx_i = block*1024 + t + 256*i (coalesced).
    const int blockbase = blockIdx.x * (256 * PPT);
    const int b  = blockbase >> 16;            // uniform: blocks never straddle
    const int p0 = blockbase & (HW - 1);
    const int base0 = b * CHW + p0 + t;        // pixel i at base0 + 256*i

    float z0[PPT], z1[PPT], z2[PPT];
    f2 Z0[PPT], Z1[PPT], Z2[PPT], ZS[PPT];
#pragma unroll
    for (int i = 0; i < PPT; ++i) {
        const int base = base0 + 256 * i;
        z0[i] = z[base];
        z1[i] = z[base + HW];
        z2[i] = z[base + 2 * HW];
        float zs;
        {
#pragma clang fp contract(off)
            zs = z0[i] * z0[i] + z1[i] * z1[i] + z2[i] * z2[i];
        }
        Z0[i] = (f2){z0[i], z0[i]};
        Z1[i] = (f2){z1[i], z1[i]};
        Z2[i] = (f2){z2[i], z2[i]};
        ZS[i] = (f2){zs, zs};
    }

    float best[PPT];
    int   bi[PPT];
#pragma unroll
    for (int i = 0; i < PPT; ++i) { best[i] = 3.4e38f; bi[i] = 0; }

#pragma unroll 4
    for (int j = 0; j < KPAL / 2; ++j) {
        const Pair c = stab[j];                 // uniform addr -> broadcast
#pragma unroll
        for (int i = 0; i < PPT; ++i) {
            f2 m0 = pk_mul(Z0[i], c.x);               // z0*cx      (k, k+1)
            f2 a0 = pk_add(m0, pk_mul(Z1[i], c.y));   // + z1*cy  left-assoc
            f2 cr = pk_add(a0, pk_mul(Z2[i], c.z));   // + z2*cz  = cross
            f2 n  = pk_add(cr, cr);                   // 2*cross (exact)
            f2 s0 = pk_sub(ZS[i], n);                 // z2s - 2*cross
            f2 d  = pk_add(s0, c.w);                  // + t2
            if (d.x < best[i]) { best[i] = d.x; bi[i] = 2 * j; }
            if (d.y < best[i]) { best[i] = d.y; bi[i] = 2 * j + 1; }
        }
    }

    float lsum = 0.0f;
#pragma unroll
    for (int i = 0; i < PPT; ++i) {
        const int base = base0 + 256 * i;
        const float c0 = table[3 * bi[i] + 0];   // divergent, L1-hot 6 KB
        const float c1 = table[3 * bi[i] + 1];
        const float c2 = table[3 * bi[i] + 2];
        out[base]          = c0;
        out[base + HW]     = c1;
        out[base + 2 * HW] = c2;
        const float d0 = c0 - z0[i], d1 = c1 - z1[i], d2v = c2 - z2[i];
        lsum += d0 * d0 + d1 * d1 + d2v * d2v;
    }

    for (int off = 32; off > 0; off >>= 1)
        lsum += __shfl_down(lsum, off);

    __shared__ float wsum[4];
    const int wid = t >> 6;
    if ((t & 63) == 0) wsum[wid] = lsum;
    __syncthreads();
    if (t == 0) {
        const float s = wsum[0] + wsum[1] + wsum[2] + wsum[3];
        atomicAdd(loss, s * (11.0f / (float)NELEM));
    }
}

extern "C" void kernel_launch(void* const* d_in, const int* in_sizes, int n_in,
                              void* d_out, int out_size, void* d_ws, size_t ws_size,
                              hipStream_t stream)
{
    const float* z     = (const float*)d_in[0];
    const float* table = (const float*)d_in[1];
    float* out  = (float*)d_out;
    float* loss = out + NELEM;

    hipMemsetAsync(loss, 0, sizeof(float), stream);
    vq_kernel<<<NPIX / (256 * PPT), 256, 0, stream>>>(z, table, out, loss);
}